// Round 6
// baseline (207.516 us; speedup 1.0000x reference)
//
#include <hip/hip_runtime.h>

#define NBATCH 4
#define CIN 256
#define CATT 32
#define NPIX 4096

static constexpr float LOG2E_F = 1.4426950408889634f;

typedef __attribute__((ext_vector_type(8))) short bf16x8;
typedef __attribute__((ext_vector_type(4))) float f32x4;
typedef __attribute__((ext_vector_type(16))) float f32x16;
typedef __attribute__((ext_vector_type(4))) unsigned u32x4;
typedef __attribute__((ext_vector_type(2))) unsigned u32x2;

__device__ __forceinline__ unsigned short f2bf_rne(float f) {
    unsigned u = __builtin_bit_cast(unsigned, f);
    return (unsigned short)((u + 0x7fffu + ((u >> 16) & 1u)) >> 16);
}
__device__ __forceinline__ float bf2f(unsigned short h) {
    unsigned u = (unsigned)h << 16;
    return __builtin_bit_cast(float, u);
}
// 8 consecutive f32 -> bf16 hi + bf16 lo fragments (hi+lo ~ 2^-17 rel error)
__device__ __forceinline__ void split8(const float* p, bf16x8& hi, bf16x8& lo) {
    const float4 a = *reinterpret_cast<const float4*>(p);
    const float4 b = *reinterpret_cast<const float4*>(p + 4);
    const float f[8] = {a.x, a.y, a.z, a.w, b.x, b.y, b.z, b.w};
    #pragma unroll
    for (int e = 0; e < 8; ++e) {
        const unsigned short h = f2bf_rne(f[e]);
        hi[e] = (short)h;
        lo[e] = (short)f2bf_rne(f[e] - bf2f(h));
    }
}
__device__ __forceinline__ bf16x8 cvt8(const float* p) {
    const float4 a = *reinterpret_cast<const float4*>(p);
    const float4 b = *reinterpret_cast<const float4*>(p + 4);
    const float f[8] = {a.x, a.y, a.z, a.w, b.x, b.y, b.z, b.w};
    bf16x8 r;
    #pragma unroll
    for (int e = 0; e < 8; ++e) r[e] = (short)f2bf_rne(f[e]);
    return r;
}

// ---------------------------------------------------------------------------
// K0: x[b][c][n] f32 -> xT[b][n][256] bf16 (LDS tile transpose 64c x 64n)
// grid (64, 4, 4), block 256.  (unchanged from R5)
// ---------------------------------------------------------------------------
__global__ __launch_bounds__(256, 2)
void transpose_kernel(const float* __restrict__ x, unsigned short* __restrict__ xT)
{
    __shared__ unsigned short sT[64][68];
    const int t = threadIdx.x;
    const int nblk = blockIdx.x * 64;
    const int cblk = blockIdx.y * 64;
    const int b = blockIdx.z;
    const float* xb = x + ((size_t)b * CIN + cblk) * NPIX + nblk;
    const int lc = t >> 2, ln = (t & 3) << 4;
    #pragma unroll
    for (int u = 0; u < 4; ++u) {
        const float4 v = *reinterpret_cast<const float4*>(&xb[(size_t)lc * NPIX + ln + 4 * u]);
        sT[ln + 4 * u + 0][lc] = f2bf_rne(v.x);
        sT[ln + 4 * u + 1][lc] = f2bf_rne(v.y);
        sT[ln + 4 * u + 2][lc] = f2bf_rne(v.z);
        sT[ln + 4 * u + 3][lc] = f2bf_rne(v.w);
    }
    __syncthreads();
    const int rn = t >> 2, cs = (t & 3) << 4;
    const uint2 d0 = *reinterpret_cast<const uint2*>(&sT[rn][cs + 0]);
    const uint2 d1 = *reinterpret_cast<const uint2*>(&sT[rn][cs + 4]);
    const uint2 d2 = *reinterpret_cast<const uint2*>(&sT[rn][cs + 8]);
    const uint2 d3 = *reinterpret_cast<const uint2*>(&sT[rn][cs + 12]);
    unsigned short* dst = xT + ((size_t)b * NPIX + nblk + rn) * CIN + cblk + cs;
    *reinterpret_cast<uint4*>(dst)     = make_uint4(d0.x, d0.y, d1.x, d1.y);
    *reinterpret_cast<uint4*>(dst + 8) = make_uint4(d2.x, d2.y, d3.x, d3.y);
}

// ---------------------------------------------------------------------------
// K1: q/k projection via MFMA, W split hi/lo (bf16).  (unchanged from R5)
// ---------------------------------------------------------------------------
__global__ __launch_bounds__(256, 2)
void proj_qk_kernel(const float* __restrict__ Wq, const float* __restrict__ bq,
                    const float* __restrict__ Wk, const float* __restrict__ bk,
                    const unsigned short* __restrict__ xT,
                    unsigned short* __restrict__ qt, unsigned short* __restrict__ kt)
{
    const int t = threadIdx.x, w = t >> 6, l = t & 63, lr = l & 15, lg = l >> 4;
    const int b = blockIdx.y;
    const int n0 = blockIdx.x * 64 + 16 * w;
    const unsigned short* xrow = xT + ((size_t)b * NPIX + n0 + lr) * CIN + lg * 8;
    f32x4 aq[2] = {{0.f,0.f,0.f,0.f},{0.f,0.f,0.f,0.f}};
    f32x4 ak2[2] = {{0.f,0.f,0.f,0.f},{0.f,0.f,0.f,0.f}};
    #pragma unroll
    for (int ks = 0; ks < 8; ++ks) {
        const int ko = ks * 32 + lg * 8;
        const bf16x8 bx = *reinterpret_cast<const bf16x8*>(xrow + ks * 32);
        #pragma unroll
        for (int mt = 0; mt < 2; ++mt) {
            bf16x8 wh, wl;
            split8(&Wq[(size_t)(mt * 16 + lr) * CIN + ko], wh, wl);
            aq[mt] = __builtin_amdgcn_mfma_f32_16x16x32_bf16(wh, bx, aq[mt], 0, 0, 0);
            aq[mt] = __builtin_amdgcn_mfma_f32_16x16x32_bf16(wl, bx, aq[mt], 0, 0, 0);
            split8(&Wk[(size_t)(mt * 16 + lr) * CIN + ko], wh, wl);
            ak2[mt] = __builtin_amdgcn_mfma_f32_16x16x32_bf16(wh, bx, ak2[mt], 0, 0, 0);
            ak2[mt] = __builtin_amdgcn_mfma_f32_16x16x32_bf16(wl, bx, ak2[mt], 0, 0, 0);
        }
    }
    #pragma unroll
    for (int mt = 0; mt < 2; ++mt) {
        const float4 b4q = *reinterpret_cast<const float4*>(&bq[16 * mt + (lg << 2)]);
        const float4 b4k = *reinterpret_cast<const float4*>(&bk[16 * mt + (lg << 2)]);
        ushort4 uq, uk;
        uq.x = f2bf_rne(LOG2E_F * (aq[mt][0] + b4q.x));
        uq.y = f2bf_rne(LOG2E_F * (aq[mt][1] + b4q.y));
        uq.z = f2bf_rne(LOG2E_F * (aq[mt][2] + b4q.z));
        uq.w = f2bf_rne(LOG2E_F * (aq[mt][3] + b4q.w));
        uk.x = f2bf_rne(ak2[mt][0] + b4k.x);
        uk.y = f2bf_rne(ak2[mt][1] + b4k.y);
        uk.z = f2bf_rne(ak2[mt][2] + b4k.z);
        uk.w = f2bf_rne(ak2[mt][3] + b4k.w);
        const size_t base = ((size_t)b * NPIX + n0 + lr) * CATT + 16 * mt + (lg << 2);
        *reinterpret_cast<ushort4*>(&qt[base]) = uq;
        *reinterpret_cast<ushort4*>(&kt[base]) = uk;
    }
}

// ---------------------------------------------------------------------------
// K2: stats via MFMA, software-pipelined.  (unchanged from R5)
// ---------------------------------------------------------------------------
__global__ __launch_bounds__(256, 2)
void stats_kernel(const unsigned short* __restrict__ qt,
                  const unsigned short* __restrict__ kt, float* __restrict__ rs)
{
    __shared__ float sred[4][16];
    const int n = blockIdx.x;
    const int b = n & 3;
    const int jblk = (n >> 2) * 32;
    const int t = threadIdx.x, w = t >> 6, l = t & 63, lr = l & 15, lg = l >> 4;
    const int jsl = w & 1;
    const int ih = w >> 1;
    const unsigned short* qb = qt + (size_t)b * NPIX * CATT;
    const unsigned short* kb = kt + (size_t)b * NPIX * CATT;

    const bf16x8 kfrag = *reinterpret_cast<const bf16x8*>(
        &kb[(size_t)(jblk + 16 * jsl + lr) * CATT + lg * 8]);
    const f32x4 zero = {0.f, 0.f, 0.f, 0.f};
    const unsigned short* qp = qb + (size_t)(ih * 2048 + lr) * CATT + lg * 8;

    float s0 = 0.f, s1 = 0.f, s2 = 0.f, s3 = 0.f;
    bf16x8 qc0 = *reinterpret_cast<const bf16x8*>(qp);
    bf16x8 qc1 = *reinterpret_cast<const bf16x8*>(qp + 16 * CATT);
    bf16x8 qc2 = *reinterpret_cast<const bf16x8*>(qp + 32 * CATT);
    bf16x8 qc3 = *reinterpret_cast<const bf16x8*>(qp + 48 * CATT);

    for (int ib = 0; ib < 2048; ib += 64) {
        bf16x8 qn0, qn1, qn2, qn3;
        const bool more = (ib + 64) < 2048;
        if (more) {
            const unsigned short* q2 = qp + (size_t)(ib + 64) * CATT;
            qn0 = *reinterpret_cast<const bf16x8*>(q2);
            qn1 = *reinterpret_cast<const bf16x8*>(q2 + 16 * CATT);
            qn2 = *reinterpret_cast<const bf16x8*>(q2 + 32 * CATT);
            qn3 = *reinterpret_cast<const bf16x8*>(q2 + 48 * CATT);
        }
        f32x4 d;
        d = __builtin_amdgcn_mfma_f32_16x16x32_bf16(kfrag, qc0, zero, 0, 0, 0);
        s0 += __builtin_amdgcn_exp2f(d[0]); s1 += __builtin_amdgcn_exp2f(d[1]);
        s2 += __builtin_amdgcn_exp2f(d[2]); s3 += __builtin_amdgcn_exp2f(d[3]);
        d = __builtin_amdgcn_mfma_f32_16x16x32_bf16(kfrag, qc1, zero, 0, 0, 0);
        s0 += __builtin_amdgcn_exp2f(d[0]); s1 += __builtin_amdgcn_exp2f(d[1]);
        s2 += __builtin_amdgcn_exp2f(d[2]); s3 += __builtin_amdgcn_exp2f(d[3]);
        d = __builtin_amdgcn_mfma_f32_16x16x32_bf16(kfrag, qc2, zero, 0, 0, 0);
        s0 += __builtin_amdgcn_exp2f(d[0]); s1 += __builtin_amdgcn_exp2f(d[1]);
        s2 += __builtin_amdgcn_exp2f(d[2]); s3 += __builtin_amdgcn_exp2f(d[3]);
        d = __builtin_amdgcn_mfma_f32_16x16x32_bf16(kfrag, qc3, zero, 0, 0, 0);
        s0 += __builtin_amdgcn_exp2f(d[0]); s1 += __builtin_amdgcn_exp2f(d[1]);
        s2 += __builtin_amdgcn_exp2f(d[2]); s3 += __builtin_amdgcn_exp2f(d[3]);
        if (more) { qc0 = qn0; qc1 = qn1; qc2 = qn2; qc3 = qn3; }
    }
    #pragma unroll
    for (int m = 1; m < 16; m <<= 1) {
        s0 += __shfl_xor(s0, m); s1 += __shfl_xor(s1, m);
        s2 += __shfl_xor(s2, m); s3 += __shfl_xor(s3, m);
    }
    if (lr == 0) {
        sred[w][(lg << 2) + 0] = s0;
        sred[w][(lg << 2) + 1] = s1;
        sred[w][(lg << 2) + 2] = s2;
        sred[w][(lg << 2) + 3] = s3;
    }
    __syncthreads();
    if (t < 32) {
        const int j16 = t & 15, js = t >> 4;
        const float s = sred[js][j16] + sred[js + 2][j16];
        rs[(size_t)b * NPIX + jblk + t] = 1.0f / s;
    }
}

// ---------------------------------------------------------------------------
// K3: v projection via MFMA -> vt[b][c][n] = bf16(gamma*rs[n]*(Wv x + bv))
// (unchanged from R5)
// ---------------------------------------------------------------------------
__global__ __launch_bounds__(256, 2)
void proj_v_kernel(const float* __restrict__ Wv, const float* __restrict__ bv,
                   const unsigned short* __restrict__ xT, const float* __restrict__ rs,
                   const float* __restrict__ gamma, unsigned short* __restrict__ vt)
{
    const int t = threadIdx.x, w = t >> 6, l = t & 63, lr = l & 15, lg = l >> 4;
    const int b = blockIdx.y;
    const int n0 = blockIdx.x * 32;
    const int cb = 64 * w;
    const unsigned short* xa = xT + ((size_t)b * NPIX + n0) * CIN;
    f32x4 acc[2][4] = {};
    #pragma unroll
    for (int ks = 0; ks < 8; ++ks) {
        const int ko = ks * 32 + lg * 8;
        bf16x8 af[2];
        #pragma unroll
        for (int mt = 0; mt < 2; ++mt)
            af[mt] = *reinterpret_cast<const bf16x8*>(&xa[(size_t)(16 * mt + lr) * CIN + ko]);
        #pragma unroll
        for (int ct = 0; ct < 4; ++ct) {
            const bf16x8 wf = cvt8(&Wv[(size_t)(cb + 16 * ct + lr) * CIN + ko]);
            #pragma unroll
            for (int mt = 0; mt < 2; ++mt)
                acc[mt][ct] = __builtin_amdgcn_mfma_f32_16x16x32_bf16(af[mt], wf, acc[mt][ct], 0, 0, 0);
        }
    }
    const float gv = gamma[0];
    #pragma unroll
    for (int mt = 0; mt < 2; ++mt) {
        const int nr = n0 + 16 * mt + (lg << 2);
        const float4 rs4 = *reinterpret_cast<const float4*>(&rs[(size_t)b * NPIX + nr]);
        #pragma unroll
        for (int ct = 0; ct < 4; ++ct) {
            const int c = cb + 16 * ct + lr;
            const float bb = bv[c];
            ushort4 u;
            u.x = f2bf_rne(gv * rs4.x * (acc[mt][ct][0] + bb));
            u.y = f2bf_rne(gv * rs4.y * (acc[mt][ct][1] + bb));
            u.z = f2bf_rne(gv * rs4.z * (acc[mt][ct][2] + bb));
            u.w = f2bf_rne(gv * rs4.w * (acc[mt][ct][3] + bb));
            *reinterpret_cast<ushort4*>(&vt[((size_t)b * CIN + c) * NPIX + nr]) = u;
        }
    }
}

// ---------------------------------------------------------------------------
// K4 (REWRITTEN): register-P fused E->exp2->PV on 32x32x16 MFMA.
// No LDS, no __syncthreads. Wave-private P: E = mfma(K,Q) gives lane
// P[j=(r&3)+8(r>>2)+4h][i=l&31]; exp2 -> cvt_pk pairs -> ONE
// permlane32_swap per pair yields the PV B-fragment directly
// (B[k=j=8h+e][n=i=l&31]) — m214v22-verified packing.
// Block: 4 waves split i (128 rows), share c-range 64 (L1 reuse of k/v).
// grid 512: b=n&3 (XCD affinity), cr=(n>>2)&3, ib=n>>4.
// ---------------------------------------------------------------------------
__global__ __launch_bounds__(256, 2)
void out_kernel(const unsigned short* __restrict__ qt,
                const unsigned short* __restrict__ kt,
                const unsigned short* __restrict__ vt,
                const float* __restrict__ x, float* __restrict__ out)
{
    const int n = blockIdx.x;
    const int b = n & 3;
    const int cr = (n >> 2) & 3;
    const int ib = n >> 4;
    const int cb = cr * 64;
    const int t = threadIdx.x, w = t >> 6, l = t & 63;
    const int lm = l & 31, h = l >> 5;
    const int i0 = ib * 128 + 32 * w;
    const unsigned short* qb = qt + (size_t)b * NPIX * CATT;
    const unsigned short* kb = kt + (size_t)b * NPIX * CATT;
    const unsigned short* vb = vt + (size_t)b * CIN * NPIX;

    // B-frag of Q (n=i=lm, k=a=8h+e, two a-halves), hoisted
    const unsigned short* qp = qb + (size_t)(i0 + lm) * CATT + 8 * h;
    const bf16x8 qf0 = *reinterpret_cast<const bf16x8*>(qp);
    const bf16x8 qf1 = *reinterpret_cast<const bf16x8*>(qp + 16);

    const unsigned short* kp  = kb + (size_t)lm * CATT + 8 * h;            // + j0*CATT
    const unsigned short* vp0 = vb + (size_t)(cb + lm) * NPIX + 8 * h;     // + j0
    const unsigned short* vp1 = vp0 + (size_t)32 * NPIX;

    f32x16 acc0 = {};
    f32x16 acc1 = {};
    const f32x16 zero16 = {};

    bf16x8 kc0 = *reinterpret_cast<const bf16x8*>(kp);
    bf16x8 kc1 = *reinterpret_cast<const bf16x8*>(kp + 16);
    bf16x8 v00 = *reinterpret_cast<const bf16x8*>(vp0);
    bf16x8 v01 = *reinterpret_cast<const bf16x8*>(vp0 + 16);
    bf16x8 v10 = *reinterpret_cast<const bf16x8*>(vp1);
    bf16x8 v11 = *reinterpret_cast<const bf16x8*>(vp1 + 16);

    for (int jb = 0; jb < 128; ++jb) {
        bf16x8 kn0, kn1, w00, w01, w10, w11;
        const bool more = jb < 127;
        if (more) {
            const int jn = (jb + 1) * 32;
            const unsigned short* kq = kp + (size_t)jn * CATT;
            kn0 = *reinterpret_cast<const bf16x8*>(kq);
            kn1 = *reinterpret_cast<const bf16x8*>(kq + 16);
            w00 = *reinterpret_cast<const bf16x8*>(vp0 + jn);
            w01 = *reinterpret_cast<const bf16x8*>(vp0 + jn + 16);
            w10 = *reinterpret_cast<const bf16x8*>(vp1 + jn);
            w11 = *reinterpret_cast<const bf16x8*>(vp1 + jn + 16);
        }
        // ---- E: 32j x 32i, two a-halves chained
        f32x16 d = __builtin_amdgcn_mfma_f32_32x32x16_bf16(kc0, qf0, zero16, 0, 0, 0);
        d = __builtin_amdgcn_mfma_f32_32x32x16_bf16(kc1, qf1, d, 0, 0, 0);
        // ---- exp2 (vt carries rs*gamma, so raw exp2 here)
        float p[16];
        #pragma unroll
        for (int r = 0; r < 16; ++r) p[r] = __builtin_amdgcn_exp2f(d[r]);
        // ---- pack: cvt_pk pairs, then one permlane32_swap per (s, s+2) pair
        unsigned c01, c23, c45, c67, c89, cAB, cCD, cEF;
        asm("v_cvt_pk_bf16_f32 %0, %1, %2" : "=v"(c01) : "v"(p[0]),  "v"(p[1]));
        asm("v_cvt_pk_bf16_f32 %0, %1, %2" : "=v"(c23) : "v"(p[2]),  "v"(p[3]));
        asm("v_cvt_pk_bf16_f32 %0, %1, %2" : "=v"(c45) : "v"(p[4]),  "v"(p[5]));
        asm("v_cvt_pk_bf16_f32 %0, %1, %2" : "=v"(c67) : "v"(p[6]),  "v"(p[7]));
        asm("v_cvt_pk_bf16_f32 %0, %1, %2" : "=v"(c89) : "v"(p[8]),  "v"(p[9]));
        asm("v_cvt_pk_bf16_f32 %0, %1, %2" : "=v"(cAB) : "v"(p[10]), "v"(p[11]));
        asm("v_cvt_pk_bf16_f32 %0, %1, %2" : "=v"(cCD) : "v"(p[12]), "v"(p[13]));
        asm("v_cvt_pk_bf16_f32 %0, %1, %2" : "=v"(cEF) : "v"(p[14]), "v"(p[15]));
        u32x2 s;
        s = __builtin_amdgcn_permlane32_swap(c01, c45, false, false); c01 = s[0]; c45 = s[1];
        s = __builtin_amdgcn_permlane32_swap(c23, c67, false, false); c23 = s[0]; c67 = s[1];
        s = __builtin_amdgcn_permlane32_swap(c89, cCD, false, false); c89 = s[0]; cCD = s[1];
        s = __builtin_amdgcn_permlane32_swap(cAB, cEF, false, false); cAB = s[0]; cEF = s[1];
        const bf16x8 B0 = __builtin_bit_cast(bf16x8, (u32x4){c01, c23, c45, c67});
        const bf16x8 B1 = __builtin_bit_cast(bf16x8, (u32x4){c89, cAB, cCD, cEF});
        // ---- PV: acc[c-tile] += V * P  (A=vt[m=c][k=j], B=P[k=j][n=i])
        acc0 = __builtin_amdgcn_mfma_f32_32x32x16_bf16(v00, B0, acc0, 0, 0, 0);
        acc0 = __builtin_amdgcn_mfma_f32_32x32x16_bf16(v01, B1, acc0, 0, 0, 0);
        acc1 = __builtin_amdgcn_mfma_f32_32x32x16_bf16(v10, B0, acc1, 0, 0, 0);
        acc1 = __builtin_amdgcn_mfma_f32_32x32x16_bf16(v11, B1, acc1, 0, 0, 0);
        if (more) { kc0 = kn0; kc1 = kn1; v00 = w00; v01 = w01; v10 = w10; v11 = w11; }
        if ((jb & 15) == 15) __builtin_amdgcn_s_barrier();  // phase cohesion for L1 reuse
    }

    // ---- epilogue: D[m=c][n=i]: c = cb + 32ct + (r&3)+8(r>>2)+4h, i = i0+lm
    const float* xb = x + (size_t)b * CIN * NPIX;
    float* ob = out + (size_t)b * CIN * NPIX;
    #pragma unroll
    for (int r = 0; r < 16; ++r) {
        const int crow = (r & 3) + 8 * (r >> 2) + 4 * h;
        const size_t idx0 = (size_t)(cb + crow) * NPIX + i0 + lm;
        ob[idx0] = acc0[r] + xb[idx0];
        const size_t idx1 = idx0 + (size_t)32 * NPIX;
        ob[idx1] = acc1[r] + xb[idx1];
    }
}

// ---------------------------------------------------------------------------
extern "C" void kernel_launch(void* const* d_in, const int* in_sizes, int n_in,
                              void* d_out, int out_size, void* d_ws, size_t ws_size,
                              hipStream_t stream)
{
    const float* x     = (const float*)d_in[0];
    const float* Wq    = (const float*)d_in[1];
    const float* bq    = (const float*)d_in[2];
    const float* Wk    = (const float*)d_in[3];
    const float* bk    = (const float*)d_in[4];
    const float* Wv    = (const float*)d_in[5];
    const float* bv    = (const float*)d_in[6];
    const float* gamma = (const float*)d_in[7];
    float* out = (float*)d_out;

    // workspace: xT bf16 [b][n][256] | qt,kt bf16 [b][n][32] | vt bf16 [b][c][n] | rs f32  ~18.4 MB
    unsigned short* xT = (unsigned short*)d_ws;
    unsigned short* qt = xT + (size_t)NBATCH * NPIX * CIN;
    unsigned short* kt = qt + (size_t)NBATCH * NPIX * CATT;
    unsigned short* vt = kt + (size_t)NBATCH * NPIX * CATT;
    float* rsw = (float*)(vt + (size_t)NBATCH * CIN * NPIX);

    transpose_kernel<<<dim3(NPIX / 64, CIN / 64, NBATCH), 256, 0, stream>>>(x, xT);
    proj_qk_kernel<<<dim3(NPIX / 64, NBATCH), 256, 0, stream>>>(Wq, bq, Wk, bk, xT, qt, kt);
    stats_kernel<<<dim3((NPIX / 32) * NBATCH), 256, 0, stream>>>(qt, kt, rsw);
    proj_v_kernel<<<dim3(NPIX / 32, NBATCH), 256, 0, stream>>>(Wv, bv, xT, rsw, gamma, vt);
    out_kernel<<<dim3(512), 256, 0, stream>>>(qt, kt, vt, x, out);
}

// Round 7
// 128.494 us; speedup vs baseline: 1.6150x; 1.6150x over previous
//
#include <hip/hip_runtime.h>

#define NBATCH 4
#define CIN 256
#define CATT 32
#define NPIX 4096

static constexpr float LOG2E_F = 1.4426950408889634f;

typedef __attribute__((ext_vector_type(8))) short bf16x8;
typedef __attribute__((ext_vector_type(4))) float f32x4;

__device__ __forceinline__ unsigned short f2bf_rne(float f) {
    unsigned u = __builtin_bit_cast(unsigned, f);
    return (unsigned short)((u + 0x7fffu + ((u >> 16) & 1u)) >> 16);
}
__device__ __forceinline__ float bf2f(unsigned short h) {
    unsigned u = (unsigned)h << 16;
    return __builtin_bit_cast(float, u);
}
__device__ __forceinline__ void split8(const float* p, bf16x8& hi, bf16x8& lo) {
    const float4 a = *reinterpret_cast<const float4*>(p);
    const float4 b = *reinterpret_cast<const float4*>(p + 4);
    const float f[8] = {a.x, a.y, a.z, a.w, b.x, b.y, b.z, b.w};
    #pragma unroll
    for (int e = 0; e < 8; ++e) {
        const unsigned short h = f2bf_rne(f[e]);
        hi[e] = (short)h;
        lo[e] = (short)f2bf_rne(f[e] - bf2f(h));
    }
}
__device__ __forceinline__ bf16x8 cvt8(const float* p) {
    const float4 a = *reinterpret_cast<const float4*>(p);
    const float4 b = *reinterpret_cast<const float4*>(p + 4);
    const float f[8] = {a.x, a.y, a.z, a.w, b.x, b.y, b.z, b.w};
    bf16x8 r;
    #pragma unroll
    for (int e = 0; e < 8; ++e) r[e] = (short)f2bf_rne(f[e]);
    return r;
}
// async global -> LDS, 16B per lane (dest = uniform base + lane*16)
__device__ __forceinline__ void gl_lds16(const unsigned short* g, unsigned short* l) {
    __builtin_amdgcn_global_load_lds(
        (const __attribute__((address_space(1))) unsigned int*)g,
        (__attribute__((address_space(3))) unsigned int*)l, 16, 0, 0);
}

// ---------------------------------------------------------------------------
// K0: x[b][c][n] f32 -> xT[b][n][256] bf16  (unchanged from R5)
// ---------------------------------------------------------------------------
__global__ __launch_bounds__(256, 2)
void transpose_kernel(const float* __restrict__ x, unsigned short* __restrict__ xT)
{
    __shared__ unsigned short sT[64][68];
    const int t = threadIdx.x;
    const int nblk = blockIdx.x * 64;
    const int cblk = blockIdx.y * 64;
    const int b = blockIdx.z;
    const float* xb = x + ((size_t)b * CIN + cblk) * NPIX + nblk;
    const int lc = t >> 2, ln = (t & 3) << 4;
    #pragma unroll
    for (int u = 0; u < 4; ++u) {
        const float4 v = *reinterpret_cast<const float4*>(&xb[(size_t)lc * NPIX + ln + 4 * u]);
        sT[ln + 4 * u + 0][lc] = f2bf_rne(v.x);
        sT[ln + 4 * u + 1][lc] = f2bf_rne(v.y);
        sT[ln + 4 * u + 2][lc] = f2bf_rne(v.z);
        sT[ln + 4 * u + 3][lc] = f2bf_rne(v.w);
    }
    __syncthreads();
    const int rn = t >> 2, cs = (t & 3) << 4;
    const uint2 d0 = *reinterpret_cast<const uint2*>(&sT[rn][cs + 0]);
    const uint2 d1 = *reinterpret_cast<const uint2*>(&sT[rn][cs + 4]);
    const uint2 d2 = *reinterpret_cast<const uint2*>(&sT[rn][cs + 8]);
    const uint2 d3 = *reinterpret_cast<const uint2*>(&sT[rn][cs + 12]);
    unsigned short* dst = xT + ((size_t)b * NPIX + nblk + rn) * CIN + cblk + cs;
    *reinterpret_cast<uint4*>(dst)     = make_uint4(d0.x, d0.y, d1.x, d1.y);
    *reinterpret_cast<uint4*>(dst + 8) = make_uint4(d2.x, d2.y, d3.x, d3.y);
}

// ---------------------------------------------------------------------------
// K1: q/k projection via MFMA, W split hi/lo (unchanged from R5)
// ---------------------------------------------------------------------------
__global__ __launch_bounds__(256, 2)
void proj_qk_kernel(const float* __restrict__ Wq, const float* __restrict__ bq,
                    const float* __restrict__ Wk, const float* __restrict__ bk,
                    const unsigned short* __restrict__ xT,
                    unsigned short* __restrict__ qt, unsigned short* __restrict__ kt)
{
    const int t = threadIdx.x, w = t >> 6, l = t & 63, lr = l & 15, lg = l >> 4;
    const int b = blockIdx.y;
    const int n0 = blockIdx.x * 64 + 16 * w;
    const unsigned short* xrow = xT + ((size_t)b * NPIX + n0 + lr) * CIN + lg * 8;
    f32x4 aq[2] = {{0.f,0.f,0.f,0.f},{0.f,0.f,0.f,0.f}};
    f32x4 ak2[2] = {{0.f,0.f,0.f,0.f},{0.f,0.f,0.f,0.f}};
    #pragma unroll
    for (int ks = 0; ks < 8; ++ks) {
        const int ko = ks * 32 + lg * 8;
        const bf16x8 bx = *reinterpret_cast<const bf16x8*>(xrow + ks * 32);
        #pragma unroll
        for (int mt = 0; mt < 2; ++mt) {
            bf16x8 wh, wl;
            split8(&Wq[(size_t)(mt * 16 + lr) * CIN + ko], wh, wl);
            aq[mt] = __builtin_amdgcn_mfma_f32_16x16x32_bf16(wh, bx, aq[mt], 0, 0, 0);
            aq[mt] = __builtin_amdgcn_mfma_f32_16x16x32_bf16(wl, bx, aq[mt], 0, 0, 0);
            split8(&Wk[(size_t)(mt * 16 + lr) * CIN + ko], wh, wl);
            ak2[mt] = __builtin_amdgcn_mfma_f32_16x16x32_bf16(wh, bx, ak2[mt], 0, 0, 0);
            ak2[mt] = __builtin_amdgcn_mfma_f32_16x16x32_bf16(wl, bx, ak2[mt], 0, 0, 0);
        }
    }
    #pragma unroll
    for (int mt = 0; mt < 2; ++mt) {
        const float4 b4q = *reinterpret_cast<const float4*>(&bq[16 * mt + (lg << 2)]);
        const float4 b4k = *reinterpret_cast<const float4*>(&bk[16 * mt + (lg << 2)]);
        ushort4 uq, uk;
        uq.x = f2bf_rne(LOG2E_F * (aq[mt][0] + b4q.x));
        uq.y = f2bf_rne(LOG2E_F * (aq[mt][1] + b4q.y));
        uq.z = f2bf_rne(LOG2E_F * (aq[mt][2] + b4q.z));
        uq.w = f2bf_rne(LOG2E_F * (aq[mt][3] + b4q.w));
        uk.x = f2bf_rne(ak2[mt][0] + b4k.x);
        uk.y = f2bf_rne(ak2[mt][1] + b4k.y);
        uk.z = f2bf_rne(ak2[mt][2] + b4k.z);
        uk.w = f2bf_rne(ak2[mt][3] + b4k.w);
        const size_t base = ((size_t)b * NPIX + n0 + lr) * CATT + 16 * mt + (lg << 2);
        *reinterpret_cast<ushort4*>(&qt[base]) = uq;
        *reinterpret_cast<ushort4*>(&kt[base]) = uk;
    }
}

// ---------------------------------------------------------------------------
// K2: stats via MFMA, software-pipelined (unchanged from R5)
// ---------------------------------------------------------------------------
__global__ __launch_bounds__(256, 2)
void stats_kernel(const unsigned short* __restrict__ qt,
                  const unsigned short* __restrict__ kt, float* __restrict__ rs)
{
    __shared__ float sred[4][16];
    const int n = blockIdx.x;
    const int b = n & 3;
    const int jblk = (n >> 2) * 32;
    const int t = threadIdx.x, w = t >> 6, l = t & 63, lr = l & 15, lg = l >> 4;
    const int jsl = w & 1;
    const int ih = w >> 1;
    const unsigned short* qb = qt + (size_t)b * NPIX * CATT;
    const unsigned short* kb = kt + (size_t)b * NPIX * CATT;

    const bf16x8 kfrag = *reinterpret_cast<const bf16x8*>(
        &kb[(size_t)(jblk + 16 * jsl + lr) * CATT + lg * 8]);
    const f32x4 zero = {0.f, 0.f, 0.f, 0.f};
    const unsigned short* qp = qb + (size_t)(ih * 2048 + lr) * CATT + lg * 8;

    float s0 = 0.f, s1 = 0.f, s2 = 0.f, s3 = 0.f;
    bf16x8 qc0 = *reinterpret_cast<const bf16x8*>(qp);
    bf16x8 qc1 = *reinterpret_cast<const bf16x8*>(qp + 16 * CATT);
    bf16x8 qc2 = *reinterpret_cast<const bf16x8*>(qp + 32 * CATT);
    bf16x8 qc3 = *reinterpret_cast<const bf16x8*>(qp + 48 * CATT);

    for (int ib = 0; ib < 2048; ib += 64) {
        bf16x8 qn0, qn1, qn2, qn3;
        const bool more = (ib + 64) < 2048;
        if (more) {
            const unsigned short* q2 = qp + (size_t)(ib + 64) * CATT;
            qn0 = *reinterpret_cast<const bf16x8*>(q2);
            qn1 = *reinterpret_cast<const bf16x8*>(q2 + 16 * CATT);
            qn2 = *reinterpret_cast<const bf16x8*>(q2 + 32 * CATT);
            qn3 = *reinterpret_cast<const bf16x8*>(q2 + 48 * CATT);
        }
        f32x4 d;
        d = __builtin_amdgcn_mfma_f32_16x16x32_bf16(kfrag, qc0, zero, 0, 0, 0);
        s0 += __builtin_amdgcn_exp2f(d[0]); s1 += __builtin_amdgcn_exp2f(d[1]);
        s2 += __builtin_amdgcn_exp2f(d[2]); s3 += __builtin_amdgcn_exp2f(d[3]);
        d = __builtin_amdgcn_mfma_f32_16x16x32_bf16(kfrag, qc1, zero, 0, 0, 0);
        s0 += __builtin_amdgcn_exp2f(d[0]); s1 += __builtin_amdgcn_exp2f(d[1]);
        s2 += __builtin_amdgcn_exp2f(d[2]); s3 += __builtin_amdgcn_exp2f(d[3]);
        d = __builtin_amdgcn_mfma_f32_16x16x32_bf16(kfrag, qc2, zero, 0, 0, 0);
        s0 += __builtin_amdgcn_exp2f(d[0]); s1 += __builtin_amdgcn_exp2f(d[1]);
        s2 += __builtin_amdgcn_exp2f(d[2]); s3 += __builtin_amdgcn_exp2f(d[3]);
        d = __builtin_amdgcn_mfma_f32_16x16x32_bf16(kfrag, qc3, zero, 0, 0, 0);
        s0 += __builtin_amdgcn_exp2f(d[0]); s1 += __builtin_amdgcn_exp2f(d[1]);
        s2 += __builtin_amdgcn_exp2f(d[2]); s3 += __builtin_amdgcn_exp2f(d[3]);
        if (more) { qc0 = qn0; qc1 = qn1; qc2 = qn2; qc3 = qn3; }
    }
    #pragma unroll
    for (int m = 1; m < 16; m <<= 1) {
        s0 += __shfl_xor(s0, m); s1 += __shfl_xor(s1, m);
        s2 += __shfl_xor(s2, m); s3 += __shfl_xor(s3, m);
    }
    if (lr == 0) {
        sred[w][(lg << 2) + 0] = s0;
        sred[w][(lg << 2) + 1] = s1;
        sred[w][(lg << 2) + 2] = s2;
        sred[w][(lg << 2) + 3] = s3;
    }
    __syncthreads();
    if (t < 32) {
        const int j16 = t & 15, js = t >> 4;
        const float s = sred[js][j16] + sred[js + 2][j16];
        rs[(size_t)b * NPIX + jblk + t] = 1.0f / s;
    }
}

// ---------------------------------------------------------------------------
// K3: v projection via MFMA (unchanged from R5)
// ---------------------------------------------------------------------------
__global__ __launch_bounds__(256, 2)
void proj_v_kernel(const float* __restrict__ Wv, const float* __restrict__ bv,
                   const unsigned short* __restrict__ xT, const float* __restrict__ rs,
                   const float* __restrict__ gamma, unsigned short* __restrict__ vt)
{
    const int t = threadIdx.x, w = t >> 6, l = t & 63, lr = l & 15, lg = l >> 4;
    const int b = blockIdx.y;
    const int n0 = blockIdx.x * 32;
    const int cb = 64 * w;
    const unsigned short* xa = xT + ((size_t)b * NPIX + n0) * CIN;
    f32x4 acc[2][4] = {};
    #pragma unroll
    for (int ks = 0; ks < 8; ++ks) {
        const int ko = ks * 32 + lg * 8;
        bf16x8 af[2];
        #pragma unroll
        for (int mt = 0; mt < 2; ++mt)
            af[mt] = *reinterpret_cast<const bf16x8*>(&xa[(size_t)(16 * mt + lr) * CIN + ko]);
        #pragma unroll
        for (int ct = 0; ct < 4; ++ct) {
            const bf16x8 wf = cvt8(&Wv[(size_t)(cb + 16 * ct + lr) * CIN + ko]);
            #pragma unroll
            for (int mt = 0; mt < 2; ++mt)
                acc[mt][ct] = __builtin_amdgcn_mfma_f32_16x16x32_bf16(af[mt], wf, acc[mt][ct], 0, 0, 0);
        }
    }
    const float gv = gamma[0];
    #pragma unroll
    for (int mt = 0; mt < 2; ++mt) {
        const int nr = n0 + 16 * mt + (lg << 2);
        const float4 rs4 = *reinterpret_cast<const float4*>(&rs[(size_t)b * NPIX + nr]);
        #pragma unroll
        for (int ct = 0; ct < 4; ++ct) {
            const int c = cb + 16 * ct + lr;
            const float bb = bv[c];
            ushort4 u;
            u.x = f2bf_rne(gv * rs4.x * (acc[mt][ct][0] + bb));
            u.y = f2bf_rne(gv * rs4.y * (acc[mt][ct][1] + bb));
            u.z = f2bf_rne(gv * rs4.z * (acc[mt][ct][2] + bb));
            u.w = f2bf_rne(gv * rs4.w * (acc[mt][ct][3] + bb));
            *reinterpret_cast<ushort4*>(&vt[((size_t)b * CIN + c) * NPIX + nr]) = u;
        }
    }
}

// ---------------------------------------------------------------------------
// K4: fused E->exp2->PV with LDS-staged K/V via global_load_lds.
// Each K/V tile loaded ONCE per block (coalesced) -> L2 traffic /4 vs R5.
// Source-pre-swizzled staging (linear LDS dest, XOR'd global src), XOR'd
// ds_read. V triple-buffered (need V(jb-1) while staging V(jb+1)), K double,
// P double. One __syncthreads per iter (drains vmcnt for the async stage).
// Per iter: stage(jb+1) || E(jb)->sP || PV(jb-1).
// Block: 64 i x 128 c, 4 waves. grid 512: b=n&3, ch=(n>>2)&1, it=n>>3
// (XCD x holds one (b,ch): K+Q+V-half ~1.5MB stays L2-resident).
// ---------------------------------------------------------------------------
__global__ __launch_bounds__(256, 2)
void out_kernel(const unsigned short* __restrict__ qt,
                const unsigned short* __restrict__ kt,
                const unsigned short* __restrict__ vt,
                const float* __restrict__ x, float* __restrict__ out)
{
    __shared__ unsigned short sV[3][128 * 64];  // [slot][c(128) x j(64)], 128B rows, chunk^=(c&7)
    __shared__ unsigned short sK[2][64 * 32];   // [slot][j(64) x a(32)], 64B rows, chunk^=(j&3)
    __shared__ unsigned short sPl[2][64 * 64];  // [i][j] bf16, 128B rows, chunk^=(i&7)
    const int n = blockIdx.x;
    const int b = n & 3;
    const int rest = n >> 2;
    const int ch = rest & 1;
    const int it = rest >> 1;
    const int iblk = it * 64;
    const int cblk = ch * 128;
    const int t = threadIdx.x, w = t >> 6, l = t & 63, lr = l & 15, lg = l >> 4;
    const unsigned short* qb = qt + (size_t)b * NPIX * CATT;
    const unsigned short* kb = kt + (size_t)b * NPIX * CATT;
    const unsigned short* vb = vt + (size_t)b * CIN * NPIX;
    const f32x4 zero = {0.f, 0.f, 0.f, 0.f};

    // Q fragments (hoisted, registers)
    bf16x8 qfrag[4];
    #pragma unroll
    for (int nt = 0; nt < 4; ++nt)
        qfrag[nt] = *reinterpret_cast<const bf16x8*>(
            &qb[(size_t)(iblk + 16 * nt + lr) * CATT + lg * 8]);

    // ---- staging source pointers (per-lane, pre-swizzled)
    // V: wave w stages chunks 4w..4w+3; chunk q: rows (4w+q)*8 + l/8, 16B piece p=l&7
    const unsigned short* vsrcq[4];
    #pragma unroll
    for (int q = 0; q < 4; ++q) {
        const int r = (4 * w + q) * 8 + (l >> 3);
        const int p = l & 7;
        vsrcq[q] = vb + (size_t)(cblk + r) * NPIX + ((p ^ (r & 7)) * 8);
    }
    // K: wave w stages chunk w: rows w*16 + l/4, 16B piece p=l&3
    const int rk = w * 16 + (l >> 2);
    const unsigned short* ksrc0 = kb + (size_t)rk * CATT + (((l & 3) ^ (rk & 3)) * 8);

    // ---- read-side byte offsets (hoisted)
    const int krow = 16 * w + lr;
    const int kbyte = krow * 64 + ((lg * 16) ^ ((krow & 3) << 4));
    const int cl0 = 32 * w + lr;        // PV A rows, mt=0
    const int cl1 = cl0 + 16;           // mt=1
    int vbyte[2][2];
    #pragma unroll
    for (int kk = 0; kk < 2; ++kk) {
        vbyte[0][kk] = cl0 * 128 + ((kk * 64 + lg * 16) ^ ((cl0 & 7) << 4));
        vbyte[1][kk] = cl1 * 128 + ((kk * 64 + lg * 16) ^ ((cl1 & 7) << 4));
    }
    // P write/read (same scheme as R5)
    const int swz = (lr & 7) << 4;
    const int wb0 = lr * 128 + (((16 * w + 4 * lg) * 2) ^ swz);
    const int rb_col0 = (16 * lg) ^ swz;
    const int rb_col1 = (64 + 16 * lg) ^ swz;

    f32x4 acc[2][4] = {};

    // ---- prologue: stage tile 0 into slots (V:0, K:0)
    #pragma unroll
    for (int q = 0; q < 4; ++q) gl_lds16(vsrcq[q], &sV[0][(4 * w + q) * 512]);
    gl_lds16(ksrc0, &sK[0][w * 512]);
    __syncthreads();

    int vs_cur = 0;  // slot holding V(jb)
    for (int jb = 0; jb < 64; ++jb) {
        const int vs_next = (vs_cur == 2) ? 0 : vs_cur + 1;
        const int vs_prev = (vs_cur == 0) ? 2 : vs_cur - 1;
        if (jb < 63) {  // stage tile jb+1
            const int jn = (jb + 1) * 64;
            #pragma unroll
            for (int q = 0; q < 4; ++q)
                gl_lds16(vsrcq[q] + jn, &sV[vs_next][(4 * w + q) * 512]);
            gl_lds16(ksrc0 + (size_t)jn * CATT, &sK[(jb + 1) & 1][w * 512]);
        }
        // ---- E(jb): K from LDS, write P -> sPl[jb&1]
        {
            const char* skp = reinterpret_cast<const char*>(&sK[jb & 1][0]);
            const bf16x8 kf = *reinterpret_cast<const bf16x8*>(skp + kbyte);
            char* spw = reinterpret_cast<char*>(&sPl[jb & 1][0]);
            #pragma unroll
            for (int nt = 0; nt < 4; ++nt) {
                const f32x4 e = __builtin_amdgcn_mfma_f32_16x16x32_bf16(kf, qfrag[nt], zero, 0, 0, 0);
                const float p0 = __builtin_amdgcn_exp2f(e[0]);
                const float p1 = __builtin_amdgcn_exp2f(e[1]);
                const float p2 = __builtin_amdgcn_exp2f(e[2]);
                const float p3 = __builtin_amdgcn_exp2f(e[3]);
                unsigned w0, w1;
                asm("v_cvt_pk_bf16_f32 %0, %1, %2" : "=v"(w0) : "v"(p0), "v"(p1));
                asm("v_cvt_pk_bf16_f32 %0, %1, %2" : "=v"(w1) : "v"(p2), "v"(p3));
                *reinterpret_cast<uint2*>(spw + wb0 + nt * 2048) = make_uint2(w0, w1);
            }
        }
        // ---- PV(jb-1): P from sPl[(jb-1)&1], V from sV[vs_prev]
        if (jb > 0) {
            const char* spr = reinterpret_cast<const char*>(&sPl[(jb - 1) & 1][0]);
            const char* svp = reinterpret_cast<const char*>(&sV[vs_prev][0]);
            #pragma unroll
            for (int kk = 0; kk < 2; ++kk) {
                const int rbc = (kk == 0) ? rb_col0 : rb_col1;
                bf16x8 pf[4];
                #pragma unroll
                for (int nt = 0; nt < 4; ++nt)
                    pf[nt] = *reinterpret_cast<const bf16x8*>(spr + lr * 128 + nt * 2048 + rbc);
                const bf16x8 v0 = *reinterpret_cast<const bf16x8*>(svp + vbyte[0][kk]);
                const bf16x8 v1 = *reinterpret_cast<const bf16x8*>(svp + vbyte[1][kk]);
                __builtin_amdgcn_s_setprio(1);
                #pragma unroll
                for (int nt = 0; nt < 4; ++nt) {
                    acc[0][nt] = __builtin_amdgcn_mfma_f32_16x16x32_bf16(v0, pf[nt], acc[0][nt], 0, 0, 0);
                    acc[1][nt] = __builtin_amdgcn_mfma_f32_16x16x32_bf16(v1, pf[nt], acc[1][nt], 0, 0, 0);
                }
                __builtin_amdgcn_s_setprio(0);
            }
        }
        __syncthreads();   // drains vmcnt (staged tile ready) + orders LDS
        vs_cur = vs_next;
    }
    // ---- epilogue: PV(63): P in sPl[1], V in slot 63%3=0 == vs_prev of current
    {
        const int vs_prev = (vs_cur == 0) ? 2 : vs_cur - 1;
        const char* spr = reinterpret_cast<const char*>(&sPl[1][0]);
        const char* svp = reinterpret_cast<const char*>(&sV[vs_prev][0]);
        #pragma unroll
        for (int kk = 0; kk < 2; ++kk) {
            const int rbc = (kk == 0) ? rb_col0 : rb_col1;
            bf16x8 pf[4];
            #pragma unroll
            for (int nt = 0; nt < 4; ++nt)
                pf[nt] = *reinterpret_cast<const bf16x8*>(spr + lr * 128 + nt * 2048 + rbc);
            const bf16x8 v0 = *reinterpret_cast<const bf16x8*>(svp + vbyte[0][kk]);
            const bf16x8 v1 = *reinterpret_cast<const bf16x8*>(svp + vbyte[1][kk]);
            #pragma unroll
            for (int nt = 0; nt < 4; ++nt) {
                acc[0][nt] = __builtin_amdgcn_mfma_f32_16x16x32_bf16(v0, pf[nt], acc[0][nt], 0, 0, 0);
                acc[1][nt] = __builtin_amdgcn_mfma_f32_16x16x32_bf16(v1, pf[nt], acc[1][nt], 0, 0, 0);
            }
        }
    }

    const float* xb = x + (size_t)b * CIN * NPIX;
    float* ob = out + (size_t)b * CIN * NPIX;
    #pragma unroll
    for (int mt = 0; mt < 2; ++mt)
        #pragma unroll
        for (int nt = 0; nt < 4; ++nt)
            #pragma unroll
            for (int r = 0; r < 4; ++r) {
                const int c = cblk + 32 * w + 16 * mt + (lg << 2) + r;
                const size_t idx = (size_t)c * NPIX + iblk + 16 * nt + lr;
                ob[idx] = acc[mt][nt][r] + xb[idx];
            }
}

// ---------------------------------------------------------------------------
extern "C" void kernel_launch(void* const* d_in, const int* in_sizes, int n_in,
                              void* d_out, int out_size, void* d_ws, size_t ws_size,
                              hipStream_t stream)
{
    const float* x     = (const float*)d_in[0];
    const float* Wq    = (const float*)d_in[1];
    const float* bq    = (const float*)d_in[2];
    const float* Wk    = (const float*)d_in[3];
    const float* bk    = (const float*)d_in[4];
    const float* Wv    = (const float*)d_in[5];
    const float* bv    = (const float*)d_in[6];
    const float* gamma = (const float*)d_in[7];
    float* out = (float*)d_out;

    unsigned short* xT = (unsigned short*)d_ws;
    unsigned short* qt = xT + (size_t)NBATCH * NPIX * CIN;
    unsigned short* kt = qt + (size_t)NBATCH * NPIX * CATT;
    unsigned short* vt = kt + (size_t)NBATCH * NPIX * CATT;
    float* rsw = (float*)(vt + (size_t)NBATCH * CIN * NPIX);

    transpose_kernel<<<dim3(NPIX / 64, CIN / 64, NBATCH), 256, 0, stream>>>(x, xT);
    proj_qk_kernel<<<dim3(NPIX / 64, NBATCH), 256, 0, stream>>>(Wq, bq, Wk, bk, xT, qt, kt);
    stats_kernel<<<dim3((NPIX / 32) * NBATCH), 256, 0, stream>>>(qt, kt, rsw);
    proj_v_kernel<<<dim3(NPIX / 32, NBATCH), 256, 0, stream>>>(Wv, bv, xT, rsw, gamma, vt);
    out_kernel<<<dim3((NPIX / 64) * 2 * NBATCH), 256, 0, stream>>>(qt, kt, vt, x, out);
}

// Round 11
// 128.151 us; speedup vs baseline: 1.6193x; 1.0027x over previous
//
#include <hip/hip_runtime.h>

#define NBATCH 4
#define CIN 256
#define CATT 32
#define NPIX 4096

static constexpr float LOG2E_F = 1.4426950408889634f;

typedef __attribute__((ext_vector_type(8))) short bf16x8;
typedef __attribute__((ext_vector_type(4))) float f32x4;

__device__ __forceinline__ unsigned short f2bf_rne(float f) {
    unsigned u = __builtin_bit_cast(unsigned, f);
    return (unsigned short)((u + 0x7fffu + ((u >> 16) & 1u)) >> 16);
}
__device__ __forceinline__ float bf2f(unsigned short h) {
    unsigned u = (unsigned)h << 16;
    return __builtin_bit_cast(float, u);
}
__device__ __forceinline__ void split8(const float* p, bf16x8& hi, bf16x8& lo) {
    const float4 a = *reinterpret_cast<const float4*>(p);
    const float4 b = *reinterpret_cast<const float4*>(p + 4);
    const float f[8] = {a.x, a.y, a.z, a.w, b.x, b.y, b.z, b.w};
    #pragma unroll
    for (int e = 0; e < 8; ++e) {
        const unsigned short h = f2bf_rne(f[e]);
        hi[e] = (short)h;
        lo[e] = (short)f2bf_rne(f[e] - bf2f(h));
    }
}
__device__ __forceinline__ bf16x8 cvt8(const float* p) {
    const float4 a = *reinterpret_cast<const float4*>(p);
    const float4 b = *reinterpret_cast<const float4*>(p + 4);
    const float f[8] = {a.x, a.y, a.z, a.w, b.x, b.y, b.z, b.w};
    bf16x8 r;
    #pragma unroll
    for (int e = 0; e < 8; ++e) r[e] = (short)f2bf_rne(f[e]);
    return r;
}
// async global -> LDS, 16B per lane (dest = uniform base + lane*16)
__device__ __forceinline__ void gl_lds16(const unsigned short* g, unsigned short* l) {
    __builtin_amdgcn_global_load_lds(
        (const __attribute__((address_space(1))) unsigned int*)g,
        (__attribute__((address_space(3))) unsigned int*)l, 16, 0, 0);
}

// ---------------------------------------------------------------------------
// K0: x[b][c][n] f32 -> xT[b][n][256] bf16  (proven)
// ---------------------------------------------------------------------------
__global__ __launch_bounds__(256, 2)
void transpose_kernel(const float* __restrict__ x, unsigned short* __restrict__ xT)
{
    __shared__ unsigned short sT[64][68];
    const int t = threadIdx.x;
    const int nblk = blockIdx.x * 64;
    const int cblk = blockIdx.y * 64;
    const int b = blockIdx.z;
    const float* xb = x + ((size_t)b * CIN + cblk) * NPIX + nblk;
    const int lc = t >> 2, ln = (t & 3) << 4;
    #pragma unroll
    for (int u = 0; u < 4; ++u) {
        const float4 v = *reinterpret_cast<const float4*>(&xb[(size_t)lc * NPIX + ln + 4 * u]);
        sT[ln + 4 * u + 0][lc] = f2bf_rne(v.x);
        sT[ln + 4 * u + 1][lc] = f2bf_rne(v.y);
        sT[ln + 4 * u + 2][lc] = f2bf_rne(v.z);
        sT[ln + 4 * u + 3][lc] = f2bf_rne(v.w);
    }
    __syncthreads();
    const int rn = t >> 2, cs = (t & 3) << 4;
    const uint2 d0 = *reinterpret_cast<const uint2*>(&sT[rn][cs + 0]);
    const uint2 d1 = *reinterpret_cast<const uint2*>(&sT[rn][cs + 4]);
    const uint2 d2 = *reinterpret_cast<const uint2*>(&sT[rn][cs + 8]);
    const uint2 d3 = *reinterpret_cast<const uint2*>(&sT[rn][cs + 12]);
    unsigned short* dst = xT + ((size_t)b * NPIX + nblk + rn) * CIN + cblk + cs;
    *reinterpret_cast<uint4*>(dst)     = make_uint4(d0.x, d0.y, d1.x, d1.y);
    *reinterpret_cast<uint4*>(dst + 8) = make_uint4(d2.x, d2.y, d3.x, d3.y);
}

// ---------------------------------------------------------------------------
// K1: q/k projection via MFMA, W split hi/lo (proven)
// ---------------------------------------------------------------------------
__global__ __launch_bounds__(256, 2)
void proj_qk_kernel(const float* __restrict__ Wq, const float* __restrict__ bq,
                    const float* __restrict__ Wk, const float* __restrict__ bk,
                    const unsigned short* __restrict__ xT,
                    unsigned short* __restrict__ qt, unsigned short* __restrict__ kt)
{
    const int t = threadIdx.x, w = t >> 6, l = t & 63, lr = l & 15, lg = l >> 4;
    const int b = blockIdx.y;
    const int n0 = blockIdx.x * 64 + 16 * w;
    const unsigned short* xrow = xT + ((size_t)b * NPIX + n0 + lr) * CIN + lg * 8;
    f32x4 aq[2] = {{0.f,0.f,0.f,0.f},{0.f,0.f,0.f,0.f}};
    f32x4 ak2[2] = {{0.f,0.f,0.f,0.f},{0.f,0.f,0.f,0.f}};
    #pragma unroll
    for (int ks = 0; ks < 8; ++ks) {
        const int ko = ks * 32 + lg * 8;
        const bf16x8 bx = *reinterpret_cast<const bf16x8*>(xrow + ks * 32);
        #pragma unroll
        for (int mt = 0; mt < 2; ++mt) {
            bf16x8 wh, wl;
            split8(&Wq[(size_t)(mt * 16 + lr) * CIN + ko], wh, wl);
            aq[mt] = __builtin_amdgcn_mfma_f32_16x16x32_bf16(wh, bx, aq[mt], 0, 0, 0);
            aq[mt] = __builtin_amdgcn_mfma_f32_16x16x32_bf16(wl, bx, aq[mt], 0, 0, 0);
            split8(&Wk[(size_t)(mt * 16 + lr) * CIN + ko], wh, wl);
            ak2[mt] = __builtin_amdgcn_mfma_f32_16x16x32_bf16(wh, bx, ak2[mt], 0, 0, 0);
            ak2[mt] = __builtin_amdgcn_mfma_f32_16x16x32_bf16(wl, bx, ak2[mt], 0, 0, 0);
        }
    }
    #pragma unroll
    for (int mt = 0; mt < 2; ++mt) {
        const float4 b4q = *reinterpret_cast<const float4*>(&bq[16 * mt + (lg << 2)]);
        const float4 b4k = *reinterpret_cast<const float4*>(&bk[16 * mt + (lg << 2)]);
        ushort4 uq, uk;
        uq.x = f2bf_rne(LOG2E_F * (aq[mt][0] + b4q.x));
        uq.y = f2bf_rne(LOG2E_F * (aq[mt][1] + b4q.y));
        uq.z = f2bf_rne(LOG2E_F * (aq[mt][2] + b4q.z));
        uq.w = f2bf_rne(LOG2E_F * (aq[mt][3] + b4q.w));
        uk.x = f2bf_rne(ak2[mt][0] + b4k.x);
        uk.y = f2bf_rne(ak2[mt][1] + b4k.y);
        uk.z = f2bf_rne(ak2[mt][2] + b4k.z);
        uk.w = f2bf_rne(ak2[mt][3] + b4k.w);
        const size_t base = ((size_t)b * NPIX + n0 + lr) * CATT + 16 * mt + (lg << 2);
        *reinterpret_cast<ushort4*>(&qt[base]) = uq;
        *reinterpret_cast<ushort4*>(&kt[base]) = uk;
    }
}

// ---------------------------------------------------------------------------
// K2: stats via MFMA, software-pipelined (proven)
// ---------------------------------------------------------------------------
__global__ __launch_bounds__(256, 2)
void stats_kernel(const unsigned short* __restrict__ qt,
                  const unsigned short* __restrict__ kt, float* __restrict__ rs)
{
    __shared__ float sred[4][16];
    const int n = blockIdx.x;
    const int b = n & 3;
    const int jblk = (n >> 2) * 32;
    const int t = threadIdx.x, w = t >> 6, l = t & 63, lr = l & 15, lg = l >> 4;
    const int jsl = w & 1;
    const int ih = w >> 1;
    const unsigned short* qb = qt + (size_t)b * NPIX * CATT;
    const unsigned short* kb = kt + (size_t)b * NPIX * CATT;

    const bf16x8 kfrag = *reinterpret_cast<const bf16x8*>(
        &kb[(size_t)(jblk + 16 * jsl + lr) * CATT + lg * 8]);
    const f32x4 zero = {0.f, 0.f, 0.f, 0.f};
    const unsigned short* qp = qb + (size_t)(ih * 2048 + lr) * CATT + lg * 8;

    float s0 = 0.f, s1 = 0.f, s2 = 0.f, s3 = 0.f;
    bf16x8 qc0 = *reinterpret_cast<const bf16x8*>(qp);
    bf16x8 qc1 = *reinterpret_cast<const bf16x8*>(qp + 16 * CATT);
    bf16x8 qc2 = *reinterpret_cast<const bf16x8*>(qp + 32 * CATT);
    bf16x8 qc3 = *reinterpret_cast<const bf16x8*>(qp + 48 * CATT);

    for (int ib = 0; ib < 2048; ib += 64) {
        bf16x8 qn0, qn1, qn2, qn3;
        const bool more = (ib + 64) < 2048;
        if (more) {
            const unsigned short* q2 = qp + (size_t)(ib + 64) * CATT;
            qn0 = *reinterpret_cast<const bf16x8*>(q2);
            qn1 = *reinterpret_cast<const bf16x8*>(q2 + 16 * CATT);
            qn2 = *reinterpret_cast<const bf16x8*>(q2 + 32 * CATT);
            qn3 = *reinterpret_cast<const bf16x8*>(q2 + 48 * CATT);
        }
        f32x4 d;
        d = __builtin_amdgcn_mfma_f32_16x16x32_bf16(kfrag, qc0, zero, 0, 0, 0);
        s0 += __builtin_amdgcn_exp2f(d[0]); s1 += __builtin_amdgcn_exp2f(d[1]);
        s2 += __builtin_amdgcn_exp2f(d[2]); s3 += __builtin_amdgcn_exp2f(d[3]);
        d = __builtin_amdgcn_mfma_f32_16x16x32_bf16(kfrag, qc1, zero, 0, 0, 0);
        s0 += __builtin_amdgcn_exp2f(d[0]); s1 += __builtin_amdgcn_exp2f(d[1]);
        s2 += __builtin_amdgcn_exp2f(d[2]); s3 += __builtin_amdgcn_exp2f(d[3]);
        d = __builtin_amdgcn_mfma_f32_16x16x32_bf16(kfrag, qc2, zero, 0, 0, 0);
        s0 += __builtin_amdgcn_exp2f(d[0]); s1 += __builtin_amdgcn_exp2f(d[1]);
        s2 += __builtin_amdgcn_exp2f(d[2]); s3 += __builtin_amdgcn_exp2f(d[3]);
        d = __builtin_amdgcn_mfma_f32_16x16x32_bf16(kfrag, qc3, zero, 0, 0, 0);
        s0 += __builtin_amdgcn_exp2f(d[0]); s1 += __builtin_amdgcn_exp2f(d[1]);
        s2 += __builtin_amdgcn_exp2f(d[2]); s3 += __builtin_amdgcn_exp2f(d[3]);
        if (more) { qc0 = qn0; qc1 = qn1; qc2 = qn2; qc3 = qn3; }
    }
    #pragma unroll
    for (int m = 1; m < 16; m <<= 1) {
        s0 += __shfl_xor(s0, m); s1 += __shfl_xor(s1, m);
        s2 += __shfl_xor(s2, m); s3 += __shfl_xor(s3, m);
    }
    if (lr == 0) {
        sred[w][(lg << 2) + 0] = s0;
        sred[w][(lg << 2) + 1] = s1;
        sred[w][(lg << 2) + 2] = s2;
        sred[w][(lg << 2) + 3] = s3;
    }
    __syncthreads();
    if (t < 32) {
        const int j16 = t & 15, js = t >> 4;
        const float s = sred[js][j16] + sred[js + 2][j16];
        rs[(size_t)b * NPIX + jblk + t] = 1.0f / s;
    }
}

// ---------------------------------------------------------------------------
// K3: v projection via MFMA (proven)
// ---------------------------------------------------------------------------
__global__ __launch_bounds__(256, 2)
void proj_v_kernel(const float* __restrict__ Wv, const float* __restrict__ bv,
                   const unsigned short* __restrict__ xT, const float* __restrict__ rs,
                   const float* __restrict__ gamma, unsigned short* __restrict__ vt)
{
    const int t = threadIdx.x, w = t >> 6, l = t & 63, lr = l & 15, lg = l >> 4;
    const int b = blockIdx.y;
    const int n0 = blockIdx.x * 32;
    const int cb = 64 * w;
    const unsigned short* xa = xT + ((size_t)b * NPIX + n0) * CIN;
    f32x4 acc[2][4] = {};
    #pragma unroll
    for (int ks = 0; ks < 8; ++ks) {
        const int ko = ks * 32 + lg * 8;
        bf16x8 af[2];
        #pragma unroll
        for (int mt = 0; mt < 2; ++mt)
            af[mt] = *reinterpret_cast<const bf16x8*>(&xa[(size_t)(16 * mt + lr) * CIN + ko]);
        #pragma unroll
        for (int ct = 0; ct < 4; ++ct) {
            const bf16x8 wf = cvt8(&Wv[(size_t)(cb + 16 * ct + lr) * CIN + ko]);
            #pragma unroll
            for (int mt = 0; mt < 2; ++mt)
                acc[mt][ct] = __builtin_amdgcn_mfma_f32_16x16x32_bf16(af[mt], wf, acc[mt][ct], 0, 0, 0);
        }
    }
    const float gv = gamma[0];
    #pragma unroll
    for (int mt = 0; mt < 2; ++mt) {
        const int nr = n0 + 16 * mt + (lg << 2);
        const float4 rs4 = *reinterpret_cast<const float4*>(&rs[(size_t)b * NPIX + nr]);
        #pragma unroll
        for (int ct = 0; ct < 4; ++ct) {
            const int c = cb + 16 * ct + lr;
            const float bb = bv[c];
            ushort4 u;
            u.x = f2bf_rne(gv * rs4.x * (acc[mt][ct][0] + bb));
            u.y = f2bf_rne(gv * rs4.y * (acc[mt][ct][1] + bb));
            u.z = f2bf_rne(gv * rs4.z * (acc[mt][ct][2] + bb));
            u.w = f2bf_rne(gv * rs4.w * (acc[mt][ct][3] + bb));
            *reinterpret_cast<ushort4*>(&vt[((size_t)b * CIN + c) * NPIX + nr]) = u;
        }
    }
}

// ---------------------------------------------------------------------------
// K4: fused E->exp2->PV with LDS-staged K/V via global_load_lds (R7, proven).
// Per iter: stage(jb+1) || E(jb)->sP || PV(jb-1); one __syncthreads per iter.
// V triple-buffered, K double, P double. Source-pre-swizzled staging, XOR'd
// ds_read (HW-verified pair).
// Block: 64 i x 128 c, 4 waves. grid 512: b=n&3, ch=(n>>2)&1, it=n>>3.
// ---------------------------------------------------------------------------
__global__ __launch_bounds__(256, 2)
void out_kernel(const unsigned short* __restrict__ qt,
                const unsigned short* __restrict__ kt,
                const unsigned short* __restrict__ vt,
                const float* __restrict__ x, float* __restrict__ out)
{
    __shared__ unsigned short sV[3][128 * 64];  // [slot][c(128) x j(64)], 128B rows, piece^=(c&7)
    __shared__ unsigned short sK[2][64 * 32];   // [slot][j(64) x a(32)], 64B rows, piece^=(j&3)
    __shared__ unsigned short sPl[2][64 * 64];  // [i][j] bf16, 128B rows, piece^=(i&7)
    const int n = blockIdx.x;
    const int b = n & 3;
    const int rest = n >> 2;
    const int ch = rest & 1;
    const int it = rest >> 1;
    const int iblk = it * 64;
    const int cblk = ch * 128;
    const int t = threadIdx.x, w = t >> 6, l = t & 63, lr = l & 15, lg = l >> 4;
    const unsigned short* qb = qt + (size_t)b * NPIX * CATT;
    const unsigned short* kb = kt + (size_t)b * NPIX * CATT;
    const unsigned short* vb = vt + (size_t)b * CIN * NPIX;
    const f32x4 zero = {0.f, 0.f, 0.f, 0.f};

    // Q fragments (hoisted, registers)
    bf16x8 qfrag[4];
    #pragma unroll
    for (int nt = 0; nt < 4; ++nt)
        qfrag[nt] = *reinterpret_cast<const bf16x8*>(
            &qb[(size_t)(iblk + 16 * nt + lr) * CATT + lg * 8]);

    // ---- staging source pointers (per-lane, pre-swizzled)
    const unsigned short* vsrcq[4];
    #pragma unroll
    for (int q = 0; q < 4; ++q) {
        const int r = (4 * w + q) * 8 + (l >> 3);
        const int p = l & 7;
        vsrcq[q] = vb + (size_t)(cblk + r) * NPIX + ((p ^ (r & 7)) * 8);
    }
    const int rk = w * 16 + (l >> 2);
    const unsigned short* ksrc0 = kb + (size_t)rk * CATT + (((l & 3) ^ (rk & 3)) * 8);

    // ---- read-side byte offsets (hoisted)
    const int krow = 16 * w + lr;
    const int kbyte = krow * 64 + ((lg * 16) ^ ((krow & 3) << 4));
    const int cl0 = 32 * w + lr;
    const int cl1 = cl0 + 16;
    int vbyte[2][2];
    #pragma unroll
    for (int kk = 0; kk < 2; ++kk) {
        vbyte[0][kk] = cl0 * 128 + ((kk * 64 + lg * 16) ^ ((cl0 & 7) << 4));
        vbyte[1][kk] = cl1 * 128 + ((kk * 64 + lg * 16) ^ ((cl1 & 7) << 4));
    }
    const int swz = (lr & 7) << 4;
    const int wb0 = lr * 128 + (((16 * w + 4 * lg) * 2) ^ swz);
    const int rb_col0 = (16 * lg) ^ swz;
    const int rb_col1 = (64 + 16 * lg) ^ swz;

    f32x4 acc[2][4] = {};

    // ---- prologue: stage tile 0 into slots (V:0, K:0)
    #pragma unroll
    for (int q = 0; q < 4; ++q) gl_lds16(vsrcq[q], &sV[0][(4 * w + q) * 512]);
    gl_lds16(ksrc0, &sK[0][w * 512]);
    __syncthreads();

    int vs_cur = 0;
    for (int jb = 0; jb < 64; ++jb) {
        const int vs_next = (vs_cur == 2) ? 0 : vs_cur + 1;
        const int vs_prev = (vs_cur == 0) ? 2 : vs_cur - 1;
        if (jb < 63) {
            const int jn = (jb + 1) * 64;
            #pragma unroll
            for (int q = 0; q < 4; ++q)
                gl_lds16(vsrcq[q] + jn, &sV[vs_next][(4 * w + q) * 512]);
            gl_lds16(ksrc0 + (size_t)jn * CATT, &sK[(jb + 1) & 1][w * 512]);
        }
        // ---- E(jb): K from LDS, write P -> sPl[jb&1]
        {
            const char* skp = reinterpret_cast<const char*>(&sK[jb & 1][0]);
            const bf16x8 kf = *reinterpret_cast<const bf16x8*>(skp + kbyte);
            char* spw = reinterpret_cast<char*>(&sPl[jb & 1][0]);
            #pragma unroll
            for (int nt = 0; nt < 4; ++nt) {
                const f32x4 e = __builtin_amdgcn_mfma_f32_16x16x32_bf16(kf, qfrag[nt], zero, 0, 0, 0);
                const float p0 = __builtin_amdgcn_exp2f(e[0]);
                const float p1 = __builtin_amdgcn_exp2f(e[1]);
                const float p2 = __builtin_amdgcn_exp2f(e[2]);
                const float p3 = __builtin_amdgcn_exp2f(e[3]);
                unsigned w0, w1;
                asm("v_cvt_pk_bf16_f32 %0, %1, %2" : "=v"(w0) : "v"(p0), "v"(p1));
                asm("v_cvt_pk_bf16_f32 %0, %1, %2" : "=v"(w1) : "v"(p2), "v"(p3));
                *reinterpret_cast<uint2*>(spw + wb0 + nt * 2048) = make_uint2(w0, w1);
            }
        }
        // ---- PV(jb-1): P from sPl[(jb-1)&1], V from sV[vs_prev]
        if (jb > 0) {
            const char* spr = reinterpret_cast<const char*>(&sPl[(jb - 1) & 1][0]);
            const char* svp = reinterpret_cast<const char*>(&sV[vs_prev][0]);
            #pragma unroll
            for (int kk = 0; kk < 2; ++kk) {
                const int rbc = (kk == 0) ? rb_col0 : rb_col1;
                bf16x8 pf[4];
                #pragma unroll
                for (int nt = 0; nt < 4; ++nt)
                    pf[nt] = *reinterpret_cast<const bf16x8*>(spr + lr * 128 + nt * 2048 + rbc);
                const bf16x8 v0 = *reinterpret_cast<const bf16x8*>(svp + vbyte[0][kk]);
                const bf16x8 v1 = *reinterpret_cast<const bf16x8*>(svp + vbyte[1][kk]);
                __builtin_amdgcn_s_setprio(1);
                #pragma unroll
                for (int nt = 0; nt < 4; ++nt) {
                    acc[0][nt] = __builtin_amdgcn_mfma_f32_16x16x32_bf16(v0, pf[nt], acc[0][nt], 0, 0, 0);
                    acc[1][nt] = __builtin_amdgcn_mfma_f32_16x16x32_bf16(v1, pf[nt], acc[1][nt], 0, 0, 0);
                }
                __builtin_amdgcn_s_setprio(0);
            }
        }
        __syncthreads();   // drains vmcnt (staged tile ready) + orders LDS
        vs_cur = vs_next;
    }
    // ---- epilogue: PV(63): P in sPl[1], V in vs_prev of current
    {
        const int vs_prev = (vs_cur == 0) ? 2 : vs_cur - 1;
        const char* spr = reinterpret_cast<const char*>(&sPl[1][0]);
        const char* svp = reinterpret_cast<const char*>(&sV[vs_prev][0]);
        #pragma unroll
        for (int kk = 0; kk < 2; ++kk) {
            const int rbc = (kk == 0) ? rb_col0 : rb_col1;
            bf16x8 pf[4];
            #pragma unroll
            for (int nt = 0; nt < 4; ++nt)
                pf[nt] = *reinterpret_cast<const bf16x8*>(spr + lr * 128 + nt * 2048 + rbc);
            const bf16x8 v0 = *reinterpret_cast<const bf16x8*>(svp + vbyte[0][kk]);
            const bf16x8 v1 = *reinterpret_cast<const bf16x8*>(svp + vbyte[1][kk]);
            #pragma unroll
            for (int nt = 0; nt < 4; ++nt) {
                acc[0][nt] = __builtin_amdgcn_mfma_f32_16x16x32_bf16(v0, pf[nt], acc[0][nt], 0, 0, 0);
                acc[1][nt] = __builtin_amdgcn_mfma_f32_16x16x32_bf16(v1, pf[nt], acc[1][nt], 0, 0, 0);
            }
        }
    }

    const float* xb = x + (size_t)b * CIN * NPIX;
    float* ob = out + (size_t)b * CIN * NPIX;
    #pragma unroll
    for (int mt = 0; mt < 2; ++mt)
        #pragma unroll
        for (int nt = 0; nt < 4; ++nt)
            #pragma unroll
            for (int r = 0; r < 4; ++r) {
                const int c = cblk + 32 * w + 16 * mt + (lg << 2) + r;
                const size_t idx = (size_t)c * NPIX + iblk + 16 * nt + lr;
                ob[idx] = acc[mt][nt][r] + xb[idx];
            }
}

// ---------------------------------------------------------------------------
extern "C" void kernel_launch(void* const* d_in, const int* in_sizes, int n_in,
                              void* d_out, int out_size, void* d_ws, size_t ws_size,
                              hipStream_t stream)
{
    const float* x     = (const float*)d_in[0];
    const float* Wq    = (const float*)d_in[1];
    const float* bq    = (const float*)d_in[2];
    const float* Wk    = (const float*)d_in[3];
    const float* bk    = (const float*)d_in[4];
    const float* Wv    = (const float*)d_in[5];
    const float* bv    = (const float*)d_in[6];
    const float* gamma = (const float*)d_in[7];
    float* out = (float*)d_out;

    unsigned short* xT = (unsigned short*)d_ws;
    unsigned short* qt = xT + (size_t)NBATCH * NPIX * CIN;
    unsigned short* kt = qt + (size_t)NBATCH * NPIX * CATT;
    unsigned short* vt = kt + (size_t)NBATCH * NPIX * CATT;
    float* rsw = (float*)(vt + (size_t)NBATCH * CIN * NPIX);

    transpose_kernel<<<dim3(NPIX / 64, CIN / 64, NBATCH), 256, 0, stream>>>(x, xT);
    proj_qk_kernel<<<dim3(NPIX / 64, NBATCH), 256, 0, stream>>>(Wq, bq, Wk, bk, xT, qt, kt);
    stats_kernel<<<dim3((NPIX / 32) * NBATCH), 256, 0, stream>>>(qt, kt, rsw);
    proj_v_kernel<<<dim3(NPIX / 32, NBATCH), 256, 0, stream>>>(Wv, bv, xT, rsw, gamma, vt);
    out_kernel<<<dim3((NPIX / 64) * 2 * NBATCH), 256, 0, stream>>>(qt, kt, vt, x, out);
}